// Round 1
// baseline (440.115 us; speedup 1.0000x reference)
//
#include <hip/hip_runtime.h>
#include <hip/hip_bf16.h>

#define DIV_UP(a,b) (((a)+(b)-1)/(b))

typedef __attribute__((ext_vector_type(8))) short short8;
typedef __attribute__((ext_vector_type(4))) float floatx4;
typedef __attribute__((ext_vector_type(2))) float float2v;

// ---------- bf16 helpers (manual, deterministic RNE) ----------
static __device__ __forceinline__ unsigned short f2bf(float v) {
    unsigned u = __builtin_bit_cast(unsigned, v);
    u += 0x7fffu + ((u >> 16) & 1u);
    return (unsigned short)(u >> 16);
}
static __device__ __forceinline__ float bflo(unsigned v) {
    return __builtin_bit_cast(float, v << 16);
}
static __device__ __forceinline__ float bfhi(unsigned v) {
    return __builtin_bit_cast(float, v & 0xffff0000u);
}

static __device__ __forceinline__ float2v mk2(float a, float b) {
    float2v r; r[0] = a; r[1] = b; return r;
}
// packed fp32 FMA: one VOP3P instr does 2 channels (compiler won't emit from scalar code)
static __device__ __forceinline__ float2v pk_fma(float2v a, float2v b, float2v c) {
    float2v d;
    asm("v_pk_fma_f32 %0, %1, %2, %3" : "=v"(d) : "v"(a), "v"(b), "v"(c));
    return d;
}
// leaky_relu(z) = max(z, 0.2*z)  (holds for both signs)
static __device__ __forceinline__ float2v pk_leaky(float2v z) {
    return __builtin_elementwise_max(z, z * 0.2f);
}
static __device__ __forceinline__ float fexp2(float x) { return __builtin_amdgcn_exp2f(x); }

// load CPL bf16 -> CPL/2 packed float pairs (channels 2i,2i+1 per pair)
template <int CPL>
static __device__ __forceinline__ void load_bf16p(const unsigned short* p, float2v* d) {
    if constexpr (CPL == 8) {
        uint4 v = *(const uint4*)p;
        d[0] = mk2(bflo(v.x), bfhi(v.x));
        d[1] = mk2(bflo(v.y), bfhi(v.y));
        d[2] = mk2(bflo(v.z), bfhi(v.z));
        d[3] = mk2(bflo(v.w), bfhi(v.w));
    } else if constexpr (CPL == 4) {
        uint2 v = *(const uint2*)p;
        d[0] = mk2(bflo(v.x), bfhi(v.x));
        d[1] = mk2(bflo(v.y), bfhi(v.y));
    } else {
        unsigned v = *(const unsigned*)p;
        d[0] = mk2(bflo(v), bfhi(v));
    }
}

template <int CPL>
static __device__ __forceinline__ void store_bf16v(unsigned short* p, const float* s) {
    unsigned short tmp[CPL];
#pragma unroll
    for (int c = 0; c < CPL; ++c) tmp[c] = f2bf(s[c]);
    if constexpr (CPL == 8) *(uint4*)p = *(uint4*)tmp;
    else if constexpr (CPL == 4) *(ushort4*)p = *(ushort4*)tmp;
    else if constexpr (CPL == 2) *(ushort2*)p = *(ushort2*)tmp;
    else p[0] = tmp[0];
}

// ---------- DPP group reduction (VALU pipe, not DS) ----------
template <int CTRL>
static __device__ __forceinline__ float dpp_mv(float x) {
    int r = __builtin_amdgcn_update_dpp(0, __builtin_bit_cast(int, x), CTRL, 0xF, 0xF, false);
    return __builtin_bit_cast(float, r);
}
template <int G>
static __device__ __forceinline__ float group_reduce(float x) {
    x += dpp_mv<0xB1>(x);   // xor 1
    x += dpp_mv<0x4E>(x);   // xor 2
    x += dpp_mv<0x124>(x);  // row_ror:4
    x += dpp_mv<0x128>(x);  // row_ror:8 -> 16-lane sum
    if constexpr (G >= 32) x += __shfl_xor(x, 16, 64);
    if constexpr (G >= 64) x += __shfl_xor(x, 32, 64);
    return x;
}

// ---------- merged weight prep: 3 transposed pairs + x->bf16 ----------
static __device__ __forceinline__ void tr_pair(const float* Wa, const float* Wb, int K, int Nn,
                                               unsigned short* Wt, int i) {
    int tot = K * Nn;
    const float* W = (i < tot) ? Wa : Wb;
    unsigned short* dst = Wt + ((i < tot) ? 0 : (size_t)Nn * K);
    int ii = (i < tot) ? i : i - tot;
    int k = ii % K, n = ii / K;
    dst[(size_t)n * K + k] = f2bf(W[(size_t)k * Nn + n]);
}

__global__ void prep_all(const float* __restrict__ x,
                         const float* __restrict__ Wl1, const float* __restrict__ Wr1,
                         const float* __restrict__ Wl2, const float* __restrict__ Wr2,
                         const float* __restrict__ Wlp, const float* __restrict__ Wrp,
                         unsigned short* __restrict__ xbf,
                         unsigned short* __restrict__ wt1, unsigned short* __restrict__ wt2,
                         unsigned short* __restrict__ wt3, int N) {
    const int S1 = 2 * 64 * 1024, S2 = 2 * 1024 * 256, S3 = 2 * 256 * 384;
    int id = blockIdx.x * blockDim.x + threadIdx.x;
    if (id < S1) tr_pair(Wl1, Wr1, 64, 1024, wt1, id);
    else if (id < S1 + S2) tr_pair(Wl2, Wr2, 1024, 256, wt2, id - S1);
    else if (id < S1 + S2 + S3) tr_pair(Wlp, Wrp, 256, 384, wt3, id - S1 - S2);
    else {
        int i = id - S1 - S2 - S3;
        if (i < N * 64) xbf[i] = f2bf(x[i]);
    }
}

// ---------- MFMA bf16 GEMM: C[M,Ntot] = A[M,K] @ Bt[Ntot,K]^T ----------
__global__ __launch_bounds__(256) void gemm_mfma(
    const unsigned short* __restrict__ A, const unsigned short* __restrict__ Bt,
    unsigned short* __restrict__ C, int M, int Ntot, int K) {
    constexpr int LDA = 40;
    __shared__ unsigned short As[128 * LDA];
    __shared__ unsigned short Bs[128 * LDA];
    const int tid = threadIdx.x;
    const int m0 = blockIdx.y * 128, n0 = blockIdx.x * 128;
    const int wave = tid >> 6, lane = tid & 63;
    const int wm = (wave >> 1) * 64, wn = (wave & 1) * 64;
    const int r15 = lane & 15, quad = lane >> 4;
    const int sr = tid >> 1, skc = tid & 1;
    floatx4 acc[4][4];
#pragma unroll
    for (int i = 0; i < 4; ++i)
#pragma unroll
        for (int j = 0; j < 4; ++j) acc[i][j] = (floatx4)0.f;

    for (int k0 = 0; k0 < K; k0 += 32) {
        uint4 a0 = make_uint4(0, 0, 0, 0), a1 = make_uint4(0, 0, 0, 0);
        int am = m0 + sr;
        if (am < M) {
            const unsigned short* ap = A + (size_t)am * K + k0 + skc * 16;
            a0 = *(const uint4*)ap;
            a1 = *(const uint4*)(ap + 8);
        }
        const unsigned short* bp = Bt + (size_t)(n0 + sr) * K + k0 + skc * 16;
        uint4 b0 = *(const uint4*)bp;
        uint4 b1 = *(const uint4*)(bp + 8);
        *(uint4*)(&As[sr * LDA + skc * 16]) = a0;
        *(uint4*)(&As[sr * LDA + skc * 16 + 8]) = a1;
        *(uint4*)(&Bs[sr * LDA + skc * 16]) = b0;
        *(uint4*)(&Bs[sr * LDA + skc * 16 + 8]) = b1;
        __syncthreads();
        short8 af[4], bfr[4];
#pragma unroll
        for (int i = 0; i < 4; ++i)
            af[i] = *(const short8*)(&As[(wm + i * 16 + r15) * LDA + quad * 8]);
#pragma unroll
        for (int j = 0; j < 4; ++j)
            bfr[j] = *(const short8*)(&Bs[(wn + j * 16 + r15) * LDA + quad * 8]);
#pragma unroll
        for (int i = 0; i < 4; ++i)
#pragma unroll
            for (int j = 0; j < 4; ++j)
                acc[i][j] = __builtin_amdgcn_mfma_f32_16x16x32_bf16(af[i], bfr[j], acc[i][j], 0, 0, 0);
        __syncthreads();
    }
#pragma unroll
    for (int i = 0; i < 4; ++i)
#pragma unroll
        for (int j = 0; j < 4; ++j)
#pragma unroll
            for (int r = 0; r < 4; ++r) {
                int m = m0 + wm + i * 16 + quad * 4 + r;
                int n = n0 + wn + j * 16 + r15;
                if (m < M) C[(size_t)m * Ntot + n] = f2bf(acc[i][j][r]);
            }
}

// ---------- CSR build for BOTH graphs ----------
__global__ void count2_kernel(const int* __restrict__ dst0, const int* __restrict__ dst1,
                              int E, int N, int* __restrict__ cnt) {
    int e = blockIdx.x * blockDim.x + threadIdx.x;
    if (e < E) atomicAdd(&cnt[dst0[e]], 1);
    else if (e < 2 * E) atomicAdd(&cnt[N + dst1[e - E]], 1);
}

__global__ __launch_bounds__(1024) void scan_kernel(const int* __restrict__ cnt_all, int N,
                                                    int* __restrict__ off_all, int* __restrict__ cur_all) {
    const int* cnt = cnt_all + blockIdx.x * N;
    int* off = off_all + blockIdx.x * (N + 1);
    int* cur = cur_all + blockIdx.x * N;
    __shared__ int part[1024];
    int t = threadIdx.x;
    int per = (N + 1023) >> 10;
    int base = t * per;
    int s = 0;
    for (int i = 0; i < per; ++i) { int idx = base + i; if (idx < N) s += cnt[idx]; }
    part[t] = s;
    __syncthreads();
    for (int d2 = 1; d2 < 1024; d2 <<= 1) {
        int v = (t >= d2) ? part[t - d2] : 0;
        __syncthreads();
        part[t] += v;
        __syncthreads();
    }
    int pre = (t == 0) ? 0 : part[t - 1];
    for (int i = 0; i < per; ++i) {
        int idx = base + i;
        if (idx < N) { off[idx] = pre; cur[idx] = pre; pre += cnt[idx]; }
    }
    if (t == 1023) off[N] = part[1023];
}

__global__ void fill2_kernel(const int* __restrict__ src0, const int* __restrict__ dst0,
                             const int* __restrict__ src1, const int* __restrict__ dst1,
                             int E, int N, int* __restrict__ cur, int2* __restrict__ edges) {
    int e = blockIdx.x * blockDim.x + threadIdx.x;
    if (e < E) {
        int p = atomicAdd(&cur[dst0[e]], 1);
        edges[p] = make_int2(src0[e], e);
    } else if (e < 2 * E) {
        int i = e - E;
        int p = atomicAdd(&cur[N + dst1[i]], 1);
        edges[E + p] = make_int2(src1[i], i);
    }
}

// ---------- ea duplicate+permute: ead[j][k] = {ea[edges[j].y][k]} x2, CSR order ----------
// Removes the edges->ea pointer chase (ead is streamed by CSR index) and provides
// ready-made broadcast pairs for v_pk_fma_f32 (no v_mov duplication in the hot loop).
__global__ void dup_ea_kernel(const float* __restrict__ ea, const int2* __restrict__ edges,
                              float* __restrict__ ead, int E) {
    int j = blockIdx.x * blockDim.x + threadIdx.x;
    if (j >= E) return;
    int ey = edges[j].y;
    float4 a = ((const float4*)(ea + (size_t)ey * 8))[0];
    float4 b = ((const float4*)(ea + (size_t)ey * 8))[1];
    float4* o = (float4*)(ead + (size_t)j * 16);
    o[0] = make_float4(a.x, a.x, a.y, a.y);
    o[1] = make_float4(a.z, a.z, a.w, a.w);
    o[2] = make_float4(b.x, b.x, b.y, b.y);
    o[3] = make_float4(b.z, b.z, b.w, b.w);
}

// ---------- fused attention (HASE), packed-fp32 version ----------
// att2 is pre-scaled by log2(e): softmax runs in exp2 domain (raw v_exp_f32).
template <int D, int CPL, int QP, int G, int NE>
static __device__ __forceinline__ void hase_group(
    const unsigned short* __restrict__ xlr, const float* __restrict__ ej,
    const float* wb, const float2v (&att2)[CPL / 2], const float2v (&xr2)[CPL / 2],
    const int2* ep /*uniform*/, int c0,
    float& m, float& l, float2v (&acc2)[CPL / 2]) {
    constexpr int P = CPL / 2;
    int2 e[NE];
#pragma unroll
    for (int n = 0; n < NE; ++n) e[n] = ep[n];

    float2v xv2[NE][P], z2[NE][P];
#pragma unroll
    for (int n = 0; n < NE; ++n) {
        load_bf16p<CPL>(xlr + (size_t)e[n].x * (2 * D) + c0, xv2[n]);
#pragma unroll
        for (int p = 0; p < P; ++p) z2[n][p] = xv2[n][p] + xr2[p];
    }
    // We contribution: packed FMA, ev pairs loaded pre-duplicated; k in two halves
    // to bound VGPR pressure (ev regs die between halves).
#pragma unroll
    for (int h = 0; h < 2; ++h) {
        float2v ev[NE][4];
#pragma unroll
        for (int n = 0; n < NE; ++n) {
            const float4* q = (const float4*)(ej + (size_t)n * 16 + h * 8);
            float4 t0 = q[0], t1 = q[1];
            ev[n][0] = mk2(t0.x, t0.y); ev[n][1] = mk2(t0.z, t0.w);
            ev[n][2] = mk2(t1.x, t1.y); ev[n][3] = mk2(t1.z, t1.w);
        }
#pragma unroll
        for (int kk = 0; kk < 4; ++kk) {
            int k = h * 4 + kk;
#pragma unroll
            for (int q = 0; q < CPL / 4; ++q) {
                float4 w4 = *(const float4*)(wb + k * D + q * QP);
                float2v wa = mk2(w4.x, w4.y), wc = mk2(w4.z, w4.w);
#pragma unroll
                for (int n = 0; n < NE; ++n) {
                    z2[n][2 * q]     = pk_fma(ev[n][kk], wa, z2[n][2 * q]);
                    z2[n][2 * q + 1] = pk_fma(ev[n][kk], wc, z2[n][2 * q + 1]);
                }
            }
        }
    }
    float lg[NE];
#pragma unroll
    for (int n = 0; n < NE; ++n) {
        float2v s = mk2(0.f, 0.f);
#pragma unroll
        for (int p = 0; p < P; ++p)
            s = pk_fma(att2[p], pk_leaky(z2[n][p]), s);
        lg[n] = group_reduce<G>(s[0] + s[1]);
    }
    float mn = m;
#pragma unroll
    for (int n = 0; n < NE; ++n) mn = fmaxf(mn, lg[n]);
    float sc = fexp2(m - mn);
    float pr[NE], ps = 0.f;
#pragma unroll
    for (int n = 0; n < NE; ++n) { pr[n] = fexp2(lg[n] - mn); ps += pr[n]; }
    m = mn;
    l = fmaf(l, sc, ps);
    float2v scp = mk2(sc, sc);
    float2v prp[NE];
#pragma unroll
    for (int n = 0; n < NE; ++n) prp[n] = mk2(pr[n], pr[n]);
#pragma unroll
    for (int p = 0; p < P; ++p) {
        float2v t = prp[0] * xv2[0][p];
#pragma unroll
        for (int n = 1; n < NE; ++n) t = pk_fma(prp[n], xv2[n][p], t);
        acc2[p] = pk_fma(acc2[p], scp, t);
    }
}

template <int D, int C, int CB, int WPN, bool RELU>
__global__ __launch_bounds__(256) void attn_hase(
    const unsigned short* __restrict__ xlr, const float* __restrict__ ead,
    const float* __restrict__ We, const float* __restrict__ att,
    const int2* __restrict__ edges, const int* __restrict__ off,
    const float* __restrict__ bias, unsigned short* __restrict__ outp, int N) {
    constexpr int CPL = CB / 64;
    constexpr int P = CPL / 2;
    constexpr int HW = CB / C;
    constexpr int G = 64 / HW;
    constexpr int NPB = 4 / WPN;
    constexpr int QP = CB * 4 / CPL;
    __shared__ float wsh[8 * D];
    for (int f4 = threadIdx.x; f4 < 2 * D; f4 += 256) {
        int k = f4 / (D / 4);
        int c = (f4 - k * (D / 4)) * 4;
        int b = c / CB, cc = c - b * CB;
        int ln = cc / CPL, q = (cc % CPL) / 4;
        int dst = k * (D / 4) + (b * CB + q * QP + ln * 4) / 4;
        ((float4*)wsh)[dst] = ((const float4*)We)[f4];
    }
    __syncthreads();

    const int wid = threadIdx.x >> 6, lane = threadIdx.x & 63;
    const int wv = wid % WPN, wn = wid / WPN;
    const int c0 = wv * CB + lane * CPL;
    const float* wb = wsh + wv * CB + lane * 4;

    const float L2E = 1.4426950408889634f;
    float2v att2[P];
#pragma unroll
    for (int p = 0; p < P; ++p)
        att2[p] = mk2(att[c0 + 2 * p] * L2E, att[c0 + 2 * p + 1] * L2E);

    for (int node = blockIdx.x * NPB + wn; node < N; node += gridDim.x * NPB) {
        float2v xr2[P];
        load_bf16p<CPL>(xlr + (size_t)node * (2 * D) + D + c0, xr2);
        float m = -1e30f, l = 0.f;
        float2v acc2[P];
#pragma unroll
        for (int p = 0; p < P; ++p) acc2[p] = mk2(0.f, 0.f);

        const int jb = __builtin_amdgcn_readfirstlane(off[node]);
        const int je = __builtin_amdgcn_readfirstlane(off[node + 1]);
        int j = jb;
        for (; j + 4 <= je; j += 4)
            hase_group<D, CPL, QP, G, 4>(xlr, ead + (size_t)j * 16, wb, att2, xr2,
                                         edges + j, c0, m, l, acc2);
        for (; j < je; ++j)
            hase_group<D, CPL, QP, G, 1>(xlr, ead + (size_t)j * 16, wb, att2, xr2,
                                         edges + j, c0, m, l, acc2);

        float inv = 1.f / (l + 1e-16f);
        float r[CPL];
#pragma unroll
        for (int p = 0; p < P; ++p) {
            r[2 * p]     = fmaf(acc2[p][0], inv, bias[c0 + 2 * p]);
            r[2 * p + 1] = fmaf(acc2[p][1], inv, bias[c0 + 2 * p + 1]);
        }
        if constexpr (RELU) {
#pragma unroll
            for (int c = 0; c < CPL; ++c) r[c] = fmaxf(r[c], 0.f);
        }
        store_bf16v<CPL>(outp + (size_t)node * D + c0, r);
    }
}

// ---------- fused attention, no edge_attr (layer 3), packed ----------
template <int D, int CPL, int G, int NE>
static __device__ __forceinline__ void noe_group(
    const unsigned short* __restrict__ xlr,
    const float2v (&att2)[CPL / 2], const float2v (&xr2)[CPL / 2],
    const int2* ep /*uniform*/, int c0,
    float& m, float& l, float2v (&acc2)[CPL / 2]) {
    constexpr int P = CPL / 2;
    int2 e[NE];
#pragma unroll
    for (int n = 0; n < NE; ++n) e[n] = ep[n];
    float2v xv2[NE][P];
    float lg[NE];
#pragma unroll
    for (int n = 0; n < NE; ++n)
        load_bf16p<CPL>(xlr + (size_t)e[n].x * (2 * D) + c0, xv2[n]);
#pragma unroll
    for (int n = 0; n < NE; ++n) {
        float2v s = mk2(0.f, 0.f);
#pragma unroll
        for (int p = 0; p < P; ++p) {
            float2v z = xv2[n][p] + xr2[p];
            s = pk_fma(att2[p], pk_leaky(z), s);
        }
        lg[n] = group_reduce<G>(s[0] + s[1]);
    }
    float mn = m;
#pragma unroll
    for (int n = 0; n < NE; ++n) mn = fmaxf(mn, lg[n]);
    float sc = fexp2(m - mn);
    float pr[NE], ps = 0.f;
#pragma unroll
    for (int n = 0; n < NE; ++n) { pr[n] = fexp2(lg[n] - mn); ps += pr[n]; }
    m = mn;
    l = fmaf(l, sc, ps);
    float2v scp = mk2(sc, sc);
    float2v prp[NE];
#pragma unroll
    for (int n = 0; n < NE; ++n) prp[n] = mk2(pr[n], pr[n]);
#pragma unroll
    for (int p = 0; p < P; ++p) {
        float2v t = prp[0] * xv2[0][p];
#pragma unroll
        for (int n = 1; n < NE; ++n) t = pk_fma(prp[n], xv2[n][p], t);
        acc2[p] = pk_fma(acc2[p], scp, t);
    }
}

template <int D, int C, int CB, bool RELU>
static __device__ __forceinline__ void attn_wave3(
    const unsigned short* __restrict__ xlr, const float* __restrict__ att,
    const int2* __restrict__ edges, int jb, int je,
    const float* __restrict__ bias, float* __restrict__ outp,
    int node, int cb, int lane) {
    constexpr int CPL = CB / 64;
    constexpr int P = CPL / 2;
    constexpr int HW = CB / C;
    constexpr int G = 64 / HW;
    const int c0 = cb + lane * CPL;
    const float L2E = 1.4426950408889634f;

    float2v xr2[P], att2[P];
    load_bf16p<CPL>(xlr + (size_t)node * (2 * D) + D + c0, xr2);
#pragma unroll
    for (int p = 0; p < P; ++p)
        att2[p] = mk2(att[c0 + 2 * p] * L2E, att[c0 + 2 * p + 1] * L2E);

    float m = -1e30f, l = 0.f;
    float2v acc2[P];
#pragma unroll
    for (int p = 0; p < P; ++p) acc2[p] = mk2(0.f, 0.f);

    int j = jb;
    for (; j + 4 <= je; j += 4)
        noe_group<D, CPL, G, 4>(xlr, att2, xr2, edges + j, c0, m, l, acc2);
    for (; j < je; ++j)
        noe_group<D, CPL, G, 1>(xlr, att2, xr2, edges + j, c0, m, l, acc2);

    float inv = 1.f / (l + 1e-16f);
    float* out = outp + (size_t)node * D + c0;
    float tmp[CPL];
#pragma unroll
    for (int p = 0; p < P; ++p) {
        float r0 = fmaf(acc2[p][0], inv, bias[c0 + 2 * p]);
        float r1 = fmaf(acc2[p][1], inv, bias[c0 + 2 * p + 1]);
        if constexpr (RELU) { r0 = fmaxf(r0, 0.f); r1 = fmaxf(r1, 0.f); }
        tmp[2 * p] = r0; tmp[2 * p + 1] = r1;
    }
    if constexpr (CPL == 4) *(float4*)out = *(float4*)tmp;
    else if constexpr (CPL == 2) *(float2*)out = *(float2*)tmp;
    else out[0] = tmp[0];
}

template <int D, int C, int CB0, int CB1, bool RELU>
__global__ __launch_bounds__(256) void attn_noe(
    const unsigned short* __restrict__ xlr, const float* __restrict__ att,
    const int2* __restrict__ edges, const int* __restrict__ off,
    const float* __restrict__ bias, float* __restrict__ outp, int N) {
    const int wid = threadIdx.x >> 6, lane = threadIdx.x & 63;
    const int gw = blockIdx.x * 4 + wid;
    const int node = gw >> 1, wv = gw & 1;
    if (node >= N) return;
    const int jb = __builtin_amdgcn_readfirstlane(off[node]);
    const int je = __builtin_amdgcn_readfirstlane(off[node + 1]);
    if (wv == 0)
        attn_wave3<D, C, CB0, RELU>(xlr, att, edges, jb, je, bias, outp, node, 0, lane);
    else
        attn_wave3<D, C, CB1, RELU>(xlr, att, edges, jb, je, bias, outp, node, CB0, lane);
}

// ---------- head: 2-layer MLP on master (last) node of each graph ----------
__global__ void mlp_kernel(const float* __restrict__ h3, const int* __restrict__ nn,
                           const float* __restrict__ Wfc1, const float* __restrict__ bfc1,
                           const float* __restrict__ Wfc2, const float* __restrict__ bfc2,
                           float* __restrict__ out, int G) {
    int g = blockIdx.x, t = threadIdx.x;  // 64 threads
    int s = 0;
    for (int k = 0; k <= g; ++k) s += nn[k];
    const float* row = h3 + (size_t)(s - 1) * 384;
    float z = bfc1[t];
    for (int k = 0; k < 384; ++k) z = fmaf(row[k], Wfc1[k * 64 + t], z);
    z = fmaxf(z, 0.f);
    float v = z * Wfc2[t];
#pragma unroll
    for (int o = 32; o; o >>= 1) v += __shfl_xor(v, o, 64);
    if (t == 0) out[g] = v + bfc2[0];
}

extern "C" void kernel_launch(void* const* d_in, const int* in_sizes, int n_in,
                              void* d_out, int out_size, void* d_ws, size_t ws_size,
                              hipStream_t stream) {
    const float* x    = (const float*)d_in[0];
    const float* ea   = (const float*)d_in[1];
    const float* Wl1  = (const float*)d_in[2];
    const float* Wr1  = (const float*)d_in[3];
    const float* We1  = (const float*)d_in[4];
    const float* att1 = (const float*)d_in[5];
    const float* b1   = (const float*)d_in[6];
    const float* Wl2  = (const float*)d_in[7];
    const float* Wr2  = (const float*)d_in[8];
    const float* We2  = (const float*)d_in[9];
    const float* att2 = (const float*)d_in[10];
    const float* b2   = (const float*)d_in[11];
    const float* Wlp  = (const float*)d_in[12];
    const float* Wrp  = (const float*)d_in[13];
    const float* attp = (const float*)d_in[14];
    const float* bp   = (const float*)d_in[15];
    const float* Wfc1 = (const float*)d_in[16];
    const float* bfc1 = (const float*)d_in[17];
    const float* Wfc2 = (const float*)d_in[18];
    const float* bfc2 = (const float*)d_in[19];
    const int* ei     = (const int*)d_in[20];
    const int* eim    = (const int*)d_in[21];
    const int* nn     = (const int*)d_in[22];

    const int N = in_sizes[0] / 64;   // 20000
    const int E = in_sizes[20] / 2;   // 160000
    const int G = in_sizes[22];       // 100
    const int* src1 = ei,  *dst1 = ei + E;
    const int* srcm = eim, *dstm = eim + E;

    // ---- workspace layout (~160 MB peak, unchanged) ----
    char* w = (char*)d_ws;
    size_t o = 0;
    auto alloc = [&](size_t b) { size_t r = o; o += (b + 255) & ~(size_t)255; return r; };
    char* R1 = w + alloc((size_t)N * 2048 * 2);
    unsigned short* xlr1 = (unsigned short*)R1;
    unsigned short* xlr3 = (unsigned short*)R1;
    float* h3 = (float*)(R1 + (size_t)N * 768 * 2 + 256);
    unsigned short* h1   = (unsigned short*)(w + alloc((size_t)N * 1024 * 2));
    unsigned short* xlr2 = (unsigned short*)(w + alloc((size_t)N * 512 * 2));
    unsigned short* h2   = (unsigned short*)(w + alloc((size_t)N * 256 * 2));
    unsigned short* xbf  = (unsigned short*)(w + alloc((size_t)N * 64 * 2));
    unsigned short* wt1  = (unsigned short*)(w + alloc((size_t)2048 * 64 * 2));
    unsigned short* wt2  = (unsigned short*)(w + alloc((size_t)512 * 1024 * 2));
    unsigned short* wt3  = (unsigned short*)(w + alloc((size_t)768 * 256 * 2));
    int*  cnt   = (int*)(w + alloc((size_t)2 * N * 4));
    int*  off   = (int*)(w + alloc((size_t)2 * (N + 1) * 4));
    int*  cur   = (int*)(w + alloc((size_t)2 * N * 4));
    int2* edges = (int2*)(w + alloc((size_t)2 * E * 8 + 4096));
    (void)ws_size; (void)n_in; (void)out_size;

    // ead buffers live in DEAD regions (zero extra footprint):
    //   ead1 @ xlr2: free until gemm2 writes xlr2 (after attn1 is done)
    //   ead2 @ h1:   free after gemm2 consumed h1 (before attn2)
    float* ead1 = (float*)xlr2;   // E*16*4 = 10.24 MB <= 20.48 MB
    float* ead2 = (float*)h1;     // 10.24 MB <= 40.96 MB

    dim3 blk(256);

    // ---- weight prep (single merged launch) ----
    {
        int tot = 2 * 64 * 1024 + 2 * 1024 * 256 + 2 * 256 * 384 + N * 64;
        prep_all<<<DIV_UP(tot, 256), blk, 0, stream>>>(x, Wl1, Wr1, Wl2, Wr2, Wlp, Wrp,
                                                       xbf, wt1, wt2, wt3, N);
    }

    // ---- CSR for both graphs ----
    hipMemsetAsync(cnt, 0, (size_t)2 * N * 4, stream);
    count2_kernel<<<DIV_UP(2 * E, 256), blk, 0, stream>>>(dst1, dstm, E, N, cnt);
    scan_kernel<<<2, 1024, 0, stream>>>(cnt, N, off, cur);
    fill2_kernel<<<DIV_UP(2 * E, 256), blk, 0, stream>>>(src1, dst1, srcm, dstm, E, N, cur, edges);
    dup_ea_kernel<<<DIV_UP(E, 256), blk, 0, stream>>>(ea, edges, ead1, E);
    const int* off3 = off + (N + 1);
    int2* edges3 = edges + E;

    // ---- Layer 1: H=4, C=256, D=1024 — 2 waves/node, CPL=8, G=32, NE=4 ----
    gemm_mfma<<<dim3(2048 / 128, DIV_UP(N, 128)), blk, 0, stream>>>(xbf, wt1, xlr1, N, 2048, 64);
    attn_hase<1024, 256, 512, 2, true><<<2560, blk, 0, stream>>>(
        xlr1, ead1, We1, att1, edges, off, b1, h1, N);

    // ---- Layer 2: H=4, C=64, D=256 — 1 wave/node, CPL=4, G=16, NE=4 ----
    gemm_mfma<<<dim3(512 / 128, DIV_UP(N, 128)), blk, 0, stream>>>(h1, wt2, xlr2, N, 512, 1024);
    dup_ea_kernel<<<DIV_UP(E, 256), blk, 0, stream>>>(ea, edges, ead2, E);
    attn_hase<256, 64, 256, 1, true><<<1280, blk, 0, stream>>>(
        xlr2, ead2, We2, att2, edges, off, b2, h2, N);

    // ---- Layer 3: H=6, C=64, D=384 — 2 waves/node (roles 256/128), fp32 out, NE=4 ----
    gemm_mfma<<<dim3(768 / 128, DIV_UP(N, 128)), blk, 0, stream>>>(h2, wt3, xlr3, N, 768, 256);
    attn_noe<384, 64, 256, 128, false><<<DIV_UP(N, 2), blk, 0, stream>>>(
        xlr3, attp, edges3, off3, bp, h3, N);

    // ---- head ----
    mlp_kernel<<<G, 64, 0, stream>>>(h3, nn, Wfc1, bfc1, Wfc2, bfc2, (float*)d_out, G);
}